// Round 3
// baseline (367.883 us; speedup 1.0000x reference)
//
#include <hip/hip_runtime.h>
#include <hip/hip_fp16.h>
#include <math.h>

#define NB 8
#define CHN 256
#define HWD 96
#define PIXN (HWD*HWD)        // 9216 pixels per image
#define TOTPIX (NB*PIXN)      // 73728
#define VCN 512
#define OHW 30
#define LPP (OHW*OHW)         // 900
#define NPATCH (NB*LPP)       // 7200
#define INPD 320
#define HID 768
#define MTP 456               // padded m-tile count for 7200-row operands (57*128/16)

typedef unsigned short u16;
typedef __attribute__((ext_vector_type(8))) short bf16x8;
typedef __attribute__((ext_vector_type(8))) unsigned short us8;
typedef __attribute__((ext_vector_type(4))) float f32x4;

__device__ __forceinline__ float f4c(const float4 v, int i){
  return i==0 ? v.x : i==1 ? v.y : i==2 ? v.z : v.w;
}
__device__ __forceinline__ u16 bfrn(float f){
  unsigned u = __float_as_uint(f);
  return (u16)((u + 0x7fffu + ((u>>16)&1u)) >> 16);
}
__device__ __forceinline__ float bf2f(u16 h){
  return __uint_as_float(((unsigned)h)<<16);
}

// Fragment-order split layout for X[R][K] (row-major):
//   chunk (rt, kk, s): base = ((rt*kkc + kk)*NS + s)*512, u16 elems
//   chunk[lane*8+j] = split_s( X[rt*16 + (lane&15)][kk*32 + (lane>>4)*8 + j] )
// == the 16x16x32 bf16 MFMA A/B fragment: one coalesced 1KB wave load.

template<int NS>
__device__ __forceinline__ void split_body(const float* __restrict__ src,
                                           u16* __restrict__ dst, int K,
                                           int rt, int kk, int kkc, int lane){
  const int qr = lane>>4, col = lane&15;
  const float* s = src + (size_t)(rt*16+col)*K + kk*32 + qr*8;
  us8 h1, h2, h3;
  #pragma unroll
  for (int j=0;j<8;j++){
    float a = s[j];
    u16 x1 = bfrn(a);  float r1 = a - bf2f(x1);
    u16 x2 = bfrn(r1); float r2 = r1 - bf2f(x2);
    h1[j]=x1; h2[j]=x2; h3[j]=bfrn(r2);
  }
  size_t base = ((size_t)(rt*kkc + kk)*NS)*512 + lane*8;
  *(us8*)&dst[base]     = h1;
  *(us8*)&dst[base+512] = h2;
  if (NS == 3) *(us8*)&dst[base+1024] = h3;
}

// ---------------- merged prologue: all weight splits + w norms, 1 dispatch ----
// blocks [0,256): cw -> wf (NS3, K=256, kkc=8)
// blocks [256,736): W1 -> w1f (NS2, K=320, kkc=10)
// blocks [736,1120): W2 -> w2f (NS2, K=768, kkc=24)
// blocks [1120,1632): wnorm, one wave per v (v = b-1120)
__global__ __launch_bounds__(64) void prep_k(
    const float* __restrict__ cw, const float* __restrict__ W1,
    const float* __restrict__ W2, u16* __restrict__ wf,
    u16* __restrict__ w1f, u16* __restrict__ w2f, float* __restrict__ invw){
  int b = blockIdx.x;
  const int lane = threadIdx.x;
  if (b < 256){ split_body<3>(cw, wf, CHN, b>>3, b&7, 8, lane); return; }
  b -= 256;
  if (b < 480){ split_body<2>(W1, w1f, INPD, b/10, b%10, 10, lane); return; }
  b -= 480;
  if (b < 384){ split_body<2>(W2, w2f, HID, b/24, b%24, 24, lane); return; }
  b -= 384;
  const float4 a = *(const float4*)&cw[(size_t)b*CHN + lane*4];
  float s = fmaf(a.x,a.x, fmaf(a.y,a.y, fmaf(a.z,a.z, a.w*a.w)));
  #pragma unroll
  for (int off=32; off; off>>=1) s += __shfl_xor(s, off);
  if (lane==0) invw[b] = 1.0f/sqrtf(s);
}

// 6-term split-product MFMA: exact order preserved across rounds (numerics)
__device__ __forceinline__ void mfma6(f32x4& c, const bf16x8* A, const bf16x8* B){
  c = __builtin_amdgcn_mfma_f32_16x16x32_bf16(A[0], B[0], c, 0,0,0);
  c = __builtin_amdgcn_mfma_f32_16x16x32_bf16(A[0], B[1], c, 0,0,0);
  c = __builtin_amdgcn_mfma_f32_16x16x32_bf16(A[1], B[0], c, 0,0,0);
  c = __builtin_amdgcn_mfma_f32_16x16x32_bf16(A[0], B[2], c, 0,0,0);
  c = __builtin_amdgcn_mfma_f32_16x16x32_bf16(A[1], B[1], c, 0,0,0);
  c = __builtin_amdgcn_mfma_f32_16x16x32_bf16(A[2], B[0], c, 0,0,0);
}

// ---------------- fused: x->split staging in LDS + z GEMM (all 512 v/block) ----
// One block = 32 pixels. 4 waves, each wave: 128 v.
// K-loop is software-pipelined: B fragments ping-pong in registers (P/Q, 12
// frags each); while MFMAing the current half-kk group, the next group's 12
// global loads are in flight (compiler emits counted vmcnt). VGPR ~200 ->
// launch_bounds (256,2).
__global__ __launch_bounds__(256,2) void gemm_z_k(
    const float* __restrict__ x, const u16* __restrict__ wf,
    const float* __restrict__ invw,
    float* __restrict__ pbest, int* __restrict__ pbidx,
    __half* __restrict__ zf){
  __shared__ __align__(16) u16 afr[2*8*3*512];   // 48 KB: 2 m-tiles x 8 kk x 3 splits
  __shared__ float ssq2[4][32];
  __shared__ float rv[32][4];
  __shared__ int   ri[32][4];
  const int t = threadIdx.x;
  const int wv = t>>6, lane = t&63;
  const int col = lane&15, qr = lane>>4;
  const size_t p0 = (size_t)blockIdx.x * 32;
  const int img = (int)(p0 / PIXN);
  const int pl0 = (int)(p0 % PIXN);

  // ---- staging: thread t = pixel pi(t&31), channel octet bq(t>>5); one
  // full 16B fragment chunk per split -> conflict-free ds_write_b128 ----
  {
    const int pi = t & 31, bq = t >> 5;
    const int fr = pi & 15, mt = pi >> 4;
    const float* xb = x + ((size_t)img*CHN)*PIXN + pl0 + pi;
    float s = 0.f;
    #pragma unroll
    for (int it=0; it<4; ++it){
      const int c0 = it*64 + bq*8;               // 8 consecutive channels
      float xv[8];
      #pragma unroll
      for (int j=0;j<8;j++) xv[j] = xb[(size_t)(c0+j)*PIXN];
      us8 h1,h2,h3;
      #pragma unroll
      for (int j=0;j<8;j++){
        const float a = xv[j];
        s = fmaf(a,a,s);
        u16 x1 = bfrn(a);  float r1 = a - bf2f(x1);
        u16 x2 = bfrn(r1);
        h1[j]=x1; h2[j]=x2; h3[j]=bfrn(r1 - bf2f(x2));
      }
      const int kk = c0 >> 5, cq = (c0>>3)&3;
      u16* dstp = &afr[((mt*8+kk)*3)*512 + (cq*16+fr)*8];
      *(us8*)dstp        = h1;
      *(us8*)(dstp+512)  = h2;
      *(us8*)(dstp+1024) = h3;
    }
    s += __shfl_xor(s, 32);                      // merge the two bq of this wave
    if (lane < 32) ssq2[wv][lane] = s;
  }
  __syncthreads();

  // ---- K loop: wave wv covers v-tiles wv*8 .. wv*8+7 (128 v) ----
  f32x4 acc[2][8];
  #pragma unroll
  for (int i=0;i<2;i++)
    #pragma unroll
    for (int j=0;j<8;j++) acc[i][j] = (f32x4){0.f,0.f,0.f,0.f};
  const size_t loff = (size_t)lane*8;
  const int loff16 = lane*8;

  bf16x8 P[4][3], Q[4][3];
  #pragma unroll
  for (int q=0;q<4;q++){                         // preload P <- (kk=0, h=0)
    const size_t bb = (((size_t)(wv*8+q)*8 + 0)*3)*512 + loff;
    P[q][0] = *(const bf16x8*)&wf[bb];
    P[q][1] = *(const bf16x8*)&wf[bb+512];
    P[q][2] = *(const bf16x8*)&wf[bb+1024];
  }
  for (int kk=0; kk<8; ++kk){
    bf16x8 a0[3], a1[3];
    {
      const int ab0 = (kk*3)*512 + loff16;
      const int ab1 = ((8+kk)*3)*512 + loff16;
      a0[0] = *(const bf16x8*)&afr[ab0];
      a0[1] = *(const bf16x8*)&afr[ab0+512];
      a0[2] = *(const bf16x8*)&afr[ab0+1024];
      a1[0] = *(const bf16x8*)&afr[ab1];
      a1[1] = *(const bf16x8*)&afr[ab1+512];
      a1[2] = *(const bf16x8*)&afr[ab1+1024];
    }
    // prefetch Q <- (kk, h=1) while computing P
    #pragma unroll
    for (int q=0;q<4;q++){
      const size_t bb = (((size_t)(wv*8+4+q)*8 + kk)*3)*512 + loff;
      Q[q][0] = *(const bf16x8*)&wf[bb];
      Q[q][1] = *(const bf16x8*)&wf[bb+512];
      Q[q][2] = *(const bf16x8*)&wf[bb+1024];
    }
    #pragma unroll
    for (int q=0;q<4;q++){                       // ni = q
      mfma6(acc[0][q], a0, P[q]);
      mfma6(acc[1][q], a1, P[q]);
    }
    // prefetch P <- (kk+1, h=0) while computing Q
    if (kk < 7){
      #pragma unroll
      for (int q=0;q<4;q++){
        const size_t bb = (((size_t)(wv*8+q)*8 + (kk+1))*3)*512 + loff;
        P[q][0] = *(const bf16x8*)&wf[bb];
        P[q][1] = *(const bf16x8*)&wf[bb+512];
        P[q][2] = *(const bf16x8*)&wf[bb+1024];
      }
    }
    #pragma unroll
    for (int q=0;q<4;q++){                       // ni = 4+q
      mfma6(acc[0][4+q], a0, Q[q]);
      mfma6(acc[1][4+q], a1, Q[q]);
    }
  }

  // ---- epilogue: normalize, write zf, per-pixel argmax over all 512 v ----
  float iw[8];
  #pragma unroll
  for (int ni=0;ni<8;ni++) iw[ni] = invw[wv*128 + ni*16 + col];
  #pragma unroll
  for (int mi=0;mi<2;mi++){
    #pragma unroll
    for (int r=0;r<4;r++){
      const int P2 = mi*16 + qr*4 + r;
      const float sq = ssq2[0][P2] + ssq2[1][P2] + ssq2[2][P2] + ssq2[3][P2];
      const float ip = rsqrtf(sq);
      float bz = -1e30f; int bvi = 0;
      #pragma unroll
      for (int ni=0;ni<8;ni++){                  // ni ascending => v ascending
        const float z = f4c(*(const float4*)&acc[mi][ni], r) * ip * iw[ni];
        const int vv = wv*128 + ni*16 + col;
        zf[(p0+P2)*VCN + vv] = __float2half(z);
        if (z > bz){ bz = z; bvi = vv; }
      }
      #pragma unroll
      for (int off=1; off<16; off<<=1){
        const float oz = __shfl_xor(bz, off);
        const int  oi = __shfl_xor(bvi, off);
        if (oz > bz || (oz == bz && oi < bvi)){ bz = oz; bvi = oi; }
      }
      if (col == 0){ rv[P2][wv] = bz; ri[P2][wv] = bvi; }
    }
  }
  __syncthreads();
  if (t < 32){
    float best = rv[t][0]; int bi = ri[t][0];
    #pragma unroll
    for (int s=1;s<4;s++){                       // wave (v-quadrant) ascending
      float z2 = rv[t][s]; int i2 = ri[t][s];
      if (z2 > best || (z2 == best && i2 < bi)){ best = z2; bi = i2; }
    }
    pbest[p0+t] = best; pbidx[p0+t] = bi;
  }
}

// ---------------- per-patch selection -> inpf split-frag directly ----------------
// inpf: 2-split frag layout, R=NPATCH rows (rt=q>>4), kkc=10.
__global__ __launch_bounds__(64) void select_k(
    const float* __restrict__ x, const float* __restrict__ cw,
    const __half* __restrict__ zf,
    const float* __restrict__ pbest, const int* __restrict__ pbidx,
    u16* __restrict__ inpf){
  __shared__ float wlds[256];
  __shared__ float xcol[256];
  __shared__ float simv[64];
  const int q = blockIdx.x;
  const int lane = threadIdx.x;
  const int n = q / LPP, l = q % LPP;
  const int oy = l / OHW, ox = l % OHW;
  const int pl = (oy*3 + (lane >> 3))*HWD + (ox*3 + (lane & 7));
  const int p = n*PIXN + pl;
  const int rt = q >> 4, ql = q & 15;
  float val = pbest[p];
  int flat = pbidx[p]*64 + lane;                 // v-major flat index, pos=lane
  #pragma unroll
  for (int off=32; off>0; off>>=1){
    float ov = __shfl_xor(val, off);
    int of = __shfl_xor(flat, off);
    if (ov > val || (ov == val && of < flat)){ val = ov; flat = of; }
  }
  const int mch = flat >> 6;
  const int pos = flat & 63;
  const float ms = val;
  *(float4*)&wlds[lane*4] = *(const float4*)&cw[(size_t)mch*CHN + lane*4];
  simv[lane] = __half2float(zf[(size_t)p*VCN + mch]);
  // gather winning pixel's channel column from fp32 x (L3-resident)
  const int wpl = (oy*3 + (pos>>3))*HWD + (ox*3 + (pos&7));
  const float* xb = x + (size_t)n*CHN*PIXN + wpl;
  #pragma unroll
  for (int j=0;j<4;j++) xcol[lane*4+j] = xb[(size_t)(lane*4+j)*PIXN];
  __syncthreads();
  // integ: lanes 0..31 handle channels c0..c0+7 (one us8 chunk per split)
  if (lane < 32){
    const int kk = lane >> 2, qr = lane & 3;
    const float om = 1.0f - ms;
    const int c0 = kk*32 + qr*8;
    us8 p1, p2;
    #pragma unroll
    for (int j=0;j<8;j++){
      float v = fmaf(xcol[c0+j], ms, wlds[c0+j]*om);
      u16 s1 = bfrn(v);
      p1[j] = s1; p2[j] = bfrn(v - bf2f(s1));
    }
    const size_t ob = ((size_t)(rt*10 + kk)*2)*512 + (qr*16 + ql)*8;
    *(us8*)&inpf[ob]     = p1;
    *(us8*)&inpf[ob+512] = p2;
  }
  // sims: channels 256..319 -> chunks kk in {8,9}; 16 tasks = (s, kk, qr)
  if (lane < 16){
    const int s = lane >> 3, kk = 8 + ((lane >> 2) & 1), qr = lane & 3;
    us8 pv;
    #pragma unroll
    for (int j=0;j<8;j++){
      float v = simv[(kk-8)*32 + qr*8 + j];
      u16 s1 = bfrn(v);
      pv[j] = (s == 0) ? s1 : bfrn(v - bf2f(s1));
    }
    const size_t ob = ((size_t)(rt*10 + kk)*2 + s)*512 + (qr*16 + ql)*8;
    *(us8*)&inpf[ob] = pv;
  }
}

// ---------------- MLP layer 1: split-frag in, split-frag out (h1f) ----------------
__global__ __launch_bounds__(256,2) void mlp1_k(
    const u16* __restrict__ af, const u16* __restrict__ bf,
    const float* __restrict__ bias, u16* __restrict__ h1f){
  const int kkc = INPD >> 5;     // 10
  const int t = threadIdx.x;
  const int n0 = blockIdx.x*128, m0 = blockIdx.y*128;
  const int lane = t&63, wv = t>>6;
  const int mq = wv&1, nq = wv>>1;
  const int col = lane&15, qr = lane>>4;
  const size_t loff = (size_t)lane*8;
  const int ptA0 = (m0>>4) + mq*4;
  const int ntB0 = (n0>>4) + nq*4;
  f32x4 acc[4][4];
  #pragma unroll
  for (int i=0;i<4;i++)
    #pragma unroll
    for (int j=0;j<4;j++) acc[i][j] = (f32x4){0.f,0.f,0.f,0.f};

  for (int kk=0; kk<kkc; kk++){
    bf16x8 a[4][2];
    #pragma unroll
    for (int mi=0;mi<4;mi++){
      const size_t ab = (((size_t)(ptA0+mi)*kkc + kk)*2)*512 + loff;
      a[mi][0] = *(const bf16x8*)&af[ab];
      a[mi][1] = *(const bf16x8*)&af[ab+512];
    }
    #pragma unroll
    for (int ni=0;ni<4;ni++){
      const size_t bb = (((size_t)(ntB0+ni)*kkc + kk)*2)*512 + loff;
      const bf16x8 b1 = *(const bf16x8*)&bf[bb];
      const bf16x8 b2 = *(const bf16x8*)&bf[bb+512];
      #pragma unroll
      for (int mi=0;mi<4;mi++){
        f32x4 c = acc[mi][ni];
        c = __builtin_amdgcn_mfma_f32_16x16x32_bf16(a[mi][0], b1, c, 0,0,0);
        c = __builtin_amdgcn_mfma_f32_16x16x32_bf16(a[mi][0], b2, c, 0,0,0);
        c = __builtin_amdgcn_mfma_f32_16x16x32_bf16(a[mi][1], b1, c, 0,0,0);
        acc[mi][ni] = c;
      }
    }
  }
  float bb4[4];
  #pragma unroll
  for (int ni=0;ni<4;ni++) bb4[ni] = bias[n0 + nq*64 + ni*16 + col];
  // epilogue: leaky-relu then 2-way split store into h1f frag layout (kkc2=24).
  // pad rows (>=7200) contain finite junk; consumed only by discarded rows.
  #pragma unroll
  for (int mi=0;mi<4;mi++){
    const int rt2 = (m0>>4) + mq*4 + mi;
    #pragma unroll
    for (int r=0;r<4;r++){
      #pragma unroll
      for (int ni=0;ni<4;ni++){
        float v = f4c(*(const float4*)&acc[mi][ni], r) + bb4[ni];
        v = v > 0.f ? v : 0.2f*v;
        u16 s1 = bfrn(v);
        u16 s2 = bfrn(v - bf2f(s1));
        const int kk2 = (n0>>5) + nq*2 + (ni>>1);
        const int qn = (ni&1)*2 + (col>>3);
        const size_t ob = ((size_t)(rt2*24 + kk2)*2)*512 + (qn*16 + qr*4 + r)*8 + (col&7);
        h1f[ob] = s1; h1f[ob+512] = s2;
      }
    }
  }
}

// ---------------- MLP layer 2: split-frag in, fp32 out + tanh ----------------
__global__ __launch_bounds__(256,2) void mlp2_k(
    const u16* __restrict__ af, const u16* __restrict__ bf,
    const float* __restrict__ bias, float* __restrict__ C){
  const int kkc = HID >> 5;      // 24
  const int t = threadIdx.x;
  const int n0 = blockIdx.x*128, m0 = blockIdx.y*128;
  const int lane = t&63, wv = t>>6;
  const int mq = wv&1, nq = wv>>1;
  const int col = lane&15, qr = lane>>4;
  const size_t loff = (size_t)lane*8;
  const int ptA0 = (m0>>4) + mq*4;
  const int ntB0 = (n0>>4) + nq*4;
  f32x4 acc[4][4];
  #pragma unroll
  for (int i=0;i<4;i++)
    #pragma unroll
    for (int j=0;j<4;j++) acc[i][j] = (f32x4){0.f,0.f,0.f,0.f};

  for (int kk=0; kk<kkc; kk++){
    bf16x8 a[4][2];
    #pragma unroll
    for (int mi=0;mi<4;mi++){
      const size_t ab = (((size_t)(ptA0+mi)*kkc + kk)*2)*512 + loff;
      a[mi][0] = *(const bf16x8*)&af[ab];
      a[mi][1] = *(const bf16x8*)&af[ab+512];
    }
    #pragma unroll
    for (int ni=0;ni<4;ni++){
      const size_t bb = (((size_t)(ntB0+ni)*kkc + kk)*2)*512 + loff;
      const bf16x8 b1 = *(const bf16x8*)&bf[bb];
      const bf16x8 b2 = *(const bf16x8*)&bf[bb+512];
      #pragma unroll
      for (int mi=0;mi<4;mi++){
        f32x4 c = acc[mi][ni];
        c = __builtin_amdgcn_mfma_f32_16x16x32_bf16(a[mi][0], b1, c, 0,0,0);
        c = __builtin_amdgcn_mfma_f32_16x16x32_bf16(a[mi][0], b2, c, 0,0,0);
        c = __builtin_amdgcn_mfma_f32_16x16x32_bf16(a[mi][1], b1, c, 0,0,0);
        acc[mi][ni] = c;
      }
    }
  }
  float bb4[4];
  #pragma unroll
  for (int ni=0;ni<4;ni++) bb4[ni] = bias[n0 + nq*64 + ni*16 + col];
  #pragma unroll
  for (int mi=0;mi<4;mi++){
    #pragma unroll
    for (int r=0;r<4;r++){
      const int row = m0 + mq*64 + mi*16 + qr*4 + r;
      if (row < NPATCH){
        #pragma unroll
        for (int ni=0;ni<4;ni++){
          float v = f4c(*(const float4*)&acc[mi][ni], r) + bb4[ni];
          C[(size_t)row*CHN + n0 + nq*64 + ni*16 + col] = tanhf(v);
        }
      }
    }
  }
}

extern "C" void kernel_launch(void* const* d_in, const int* in_sizes, int n_in,
                              void* d_out, int out_size, void* d_ws, size_t ws_size,
                              hipStream_t stream){
  const float* x  = (const float*)d_in[0];
  const float* cw = (const float*)d_in[1];
  const float* W1 = (const float*)d_in[2];
  const float* b1 = (const float*)d_in[3];
  const float* W2 = (const float*)d_in[4];
  const float* b2 = (const float*)d_in[5];
  float* out = (float*)d_out;
  float* ws = (float*)d_ws;
  float* invw  = ws;                                     // 512
  float* pbest = invw + VCN;                             // TOTPIX
  int*   pbidx = (int*)(pbest + TOTPIX);                 // TOTPIX
  u16*   wf    = (u16*)(pbidx + TOTPIX);                 // 32*8*3*512 u16
  u16*   w1f   = wf + (size_t)32*8*3*512;
  u16*   w2f   = w1f + (size_t)48*10*2*512;
  u16*   inpf  = w2f + (size_t)16*24*2*512;              // MTP*10*2*512 (9.3 MB)
  __half* zf   = (__half*)(inpf + (size_t)MTP*10*2*512); // 75.5 MB
  u16*   h1f   = (u16*)zf;  // alias: zf dead after select_k; h1f written after
  // total ws use ~88 MB

  prep_k<<<1632,64,0,stream>>>(cw, W1, W2, wf, w1f, w2f, invw);
  gemm_z_k<<<TOTPIX/32,256,0,stream>>>(x, wf, invw, pbest, pbidx, zf);
  select_k<<<NPATCH,64,0,stream>>>(x, cw, zf, pbest, pbidx, inpf);
  mlp1_k<<<dim3(HID/128, (NPATCH+127)/128),256,0,stream>>>(inpf, w1f, b1, h1f);
  mlp2_k<<<dim3(CHN/128, (NPATCH+127)/128),256,0,stream>>>(h1f, w2f, b2, out);
}

// Round 4
// 318.850 us; speedup vs baseline: 1.1538x; 1.1538x over previous
//
#include <hip/hip_runtime.h>
#include <hip/hip_fp16.h>
#include <math.h>

#define NB 8
#define CHN 256
#define HWD 96
#define PIXN (HWD*HWD)        // 9216 pixels per image
#define TOTPIX (NB*PIXN)      // 73728
#define VCN 512
#define OHW 30
#define LPP (OHW*OHW)         // 900
#define NPATCH (NB*LPP)       // 7200
#define INPD 320
#define HID 768
#define MTP 456               // padded m-tile count for 7200-row operands (57*128/16)

typedef unsigned short u16;
typedef __attribute__((ext_vector_type(8))) short bf16x8;
typedef __attribute__((ext_vector_type(8))) unsigned short us8;
typedef __attribute__((ext_vector_type(4))) float f32x4;

__device__ __forceinline__ float f4c(const float4 v, int i){
  return i==0 ? v.x : i==1 ? v.y : i==2 ? v.z : v.w;
}
__device__ __forceinline__ u16 bfrn(float f){
  unsigned u = __float_as_uint(f);
  return (u16)((u + 0x7fffu + ((u>>16)&1u)) >> 16);
}
__device__ __forceinline__ float bf2f(u16 h){
  return __uint_as_float(((unsigned)h)<<16);
}

// Fragment-order split layout for X[R][K] (row-major):
//   chunk (rt, kk, s): base = ((rt*kkc + kk)*NS + s)*512, u16 elems
//   chunk[lane*8+j] = split_s( X[rt*16 + (lane&15)][kk*32 + (lane>>4)*8 + j] )
// == the 16x16x32 bf16 MFMA A/B fragment: one coalesced 1KB wave load.

template<int NS>
__device__ __forceinline__ void split_body(const float* __restrict__ src,
                                           u16* __restrict__ dst, int K,
                                           int rt, int kk, int kkc, int lane){
  const int qr = lane>>4, col = lane&15;
  const float* s = src + (size_t)(rt*16+col)*K + kk*32 + qr*8;
  us8 h1, h2, h3;
  #pragma unroll
  for (int j=0;j<8;j++){
    float a = s[j];
    u16 x1 = bfrn(a);  float r1 = a - bf2f(x1);
    u16 x2 = bfrn(r1); float r2 = r1 - bf2f(x2);
    h1[j]=x1; h2[j]=x2; h3[j]=bfrn(r2);
  }
  size_t base = ((size_t)(rt*kkc + kk)*NS)*512 + lane*8;
  *(us8*)&dst[base]     = h1;
  *(us8*)&dst[base+512] = h2;
  if (NS == 3) *(us8*)&dst[base+1024] = h3;
}

// ---------------- merged prologue: all weight splits + w norms, 1 dispatch ----
__global__ __launch_bounds__(64) void prep_k(
    const float* __restrict__ cw, const float* __restrict__ W1,
    const float* __restrict__ W2, u16* __restrict__ wf,
    u16* __restrict__ w1f, u16* __restrict__ w2f, float* __restrict__ invw){
  int b = blockIdx.x;
  const int lane = threadIdx.x;
  if (b < 256){ split_body<3>(cw, wf, CHN, b>>3, b&7, 8, lane); return; }
  b -= 256;
  if (b < 480){ split_body<2>(W1, w1f, INPD, b/10, b%10, 10, lane); return; }
  b -= 480;
  if (b < 384){ split_body<2>(W2, w2f, HID, b/24, b%24, 24, lane); return; }
  b -= 384;
  const float4 a = *(const float4*)&cw[(size_t)b*CHN + lane*4];
  float s = fmaf(a.x,a.x, fmaf(a.y,a.y, fmaf(a.z,a.z, a.w*a.w)));
  #pragma unroll
  for (int off=32; off; off>>=1) s += __shfl_xor(s, off);
  if (lane==0) invw[b] = 1.0f/sqrtf(s);
}

// 6-term split-product MFMA: exact order preserved across rounds (numerics)
__device__ __forceinline__ void mfma6(f32x4& c, const bf16x8* A, const bf16x8* B){
  c = __builtin_amdgcn_mfma_f32_16x16x32_bf16(A[0], B[0], c, 0,0,0);
  c = __builtin_amdgcn_mfma_f32_16x16x32_bf16(A[0], B[1], c, 0,0,0);
  c = __builtin_amdgcn_mfma_f32_16x16x32_bf16(A[1], B[0], c, 0,0,0);
  c = __builtin_amdgcn_mfma_f32_16x16x32_bf16(A[0], B[2], c, 0,0,0);
  c = __builtin_amdgcn_mfma_f32_16x16x32_bf16(A[1], B[1], c, 0,0,0);
  c = __builtin_amdgcn_mfma_f32_16x16x32_bf16(A[2], B[0], c, 0,0,0);
}

// ---------------- fused: x->split staging in LDS + z GEMM (all 512 v/block) ----
// One block = 32 pixels. 4 waves, each wave: 128 v.
// Round-2 proven structure: grouped 12 B-loads per half-kk, then 48 MFMAs.
// Added: s_setprio(1/0) around the MFMA cluster — runtime wave-priority
// arbitration (barrier-free K-loop => waves drift out of phase; the MFMA
// wave preempts load-issuing waves on the same SIMD). No explicit reg
// double-buffer (round-3 lesson: compiler sinks prefetch loads).
__global__ __launch_bounds__(256,3) void gemm_z_k(
    const float* __restrict__ x, const u16* __restrict__ wf,
    const float* __restrict__ invw,
    float* __restrict__ pbest, int* __restrict__ pbidx,
    __half* __restrict__ zf){
  __shared__ __align__(16) u16 afr[2*8*3*512];   // 48 KB: 2 m-tiles x 8 kk x 3 splits
  __shared__ float ssq2[4][32];
  __shared__ float rv[32][4];
  __shared__ int   ri[32][4];
  const int t = threadIdx.x;
  const int wv = t>>6, lane = t&63;
  const int col = lane&15, qr = lane>>4;
  const size_t p0 = (size_t)blockIdx.x * 32;
  const int img = (int)(p0 / PIXN);
  const int pl0 = (int)(p0 % PIXN);

  // ---- staging: thread t = pixel pi(t&31), channel octet bq(t>>5); one
  // full 16B fragment chunk per split -> conflict-free ds_write_b128 ----
  {
    const int pi = t & 31, bq = t >> 5;
    const int fr = pi & 15, mt = pi >> 4;
    const float* xb = x + ((size_t)img*CHN)*PIXN + pl0 + pi;
    float s = 0.f;
    #pragma unroll
    for (int it=0; it<4; ++it){
      const int c0 = it*64 + bq*8;               // 8 consecutive channels
      float xv[8];
      #pragma unroll
      for (int j=0;j<8;j++) xv[j] = xb[(size_t)(c0+j)*PIXN];
      us8 h1,h2,h3;
      #pragma unroll
      for (int j=0;j<8;j++){
        const float a = xv[j];
        s = fmaf(a,a,s);
        u16 x1 = bfrn(a);  float r1 = a - bf2f(x1);
        u16 x2 = bfrn(r1);
        h1[j]=x1; h2[j]=x2; h3[j]=bfrn(r1 - bf2f(x2));
      }
      const int kk = c0 >> 5, cq = (c0>>3)&3;
      u16* dstp = &afr[((mt*8+kk)*3)*512 + (cq*16+fr)*8];
      *(us8*)dstp        = h1;
      *(us8*)(dstp+512)  = h2;
      *(us8*)(dstp+1024) = h3;
    }
    s += __shfl_xor(s, 32);                      // merge the two bq of this wave
    if (lane < 32) ssq2[wv][lane] = s;
  }
  __syncthreads();

  // ---- K loop: wave wv covers v-tiles wv*8 .. wv*8+7 (128 v) ----
  f32x4 acc[2][8];
  #pragma unroll
  for (int i=0;i<2;i++)
    #pragma unroll
    for (int j=0;j<8;j++) acc[i][j] = (f32x4){0.f,0.f,0.f,0.f};
  const size_t loff = (size_t)lane*8;
  const int loff16 = lane*8;
  for (int kk=0; kk<8; ++kk){
    bf16x8 a0[3], a1[3];
    {
      const int ab0 = (kk*3)*512 + loff16;
      const int ab1 = ((8+kk)*3)*512 + loff16;
      a0[0] = *(const bf16x8*)&afr[ab0];
      a0[1] = *(const bf16x8*)&afr[ab0+512];
      a0[2] = *(const bf16x8*)&afr[ab0+1024];
      a1[0] = *(const bf16x8*)&afr[ab1];
      a1[1] = *(const bf16x8*)&afr[ab1+512];
      a1[2] = *(const bf16x8*)&afr[ab1+1024];
    }
    #pragma unroll
    for (int h=0; h<2; ++h){
      bf16x8 bg[4][3];                           // 12 grouped loads (48 VGPR)
      #pragma unroll
      for (int q=0;q<4;q++){
        const int ni = h*4+q;
        const size_t bb = (((size_t)(wv*8+ni)*8 + kk)*3)*512 + loff;
        bg[q][0] = *(const bf16x8*)&wf[bb];
        bg[q][1] = *(const bf16x8*)&wf[bb+512];
        bg[q][2] = *(const bf16x8*)&wf[bb+1024];
      }
      __builtin_amdgcn_s_setprio(1);
      #pragma unroll
      for (int q=0;q<4;q++){
        const int ni = h*4+q;
        mfma6(acc[0][ni], a0, bg[q]);
        mfma6(acc[1][ni], a1, bg[q]);
      }
      __builtin_amdgcn_s_setprio(0);
    }
  }

  // ---- epilogue: normalize, write zf, per-pixel argmax over all 512 v ----
  float iw[8];
  #pragma unroll
  for (int ni=0;ni<8;ni++) iw[ni] = invw[wv*128 + ni*16 + col];
  #pragma unroll
  for (int mi=0;mi<2;mi++){
    #pragma unroll
    for (int r=0;r<4;r++){
      const int P2 = mi*16 + qr*4 + r;
      const float sq = ssq2[0][P2] + ssq2[1][P2] + ssq2[2][P2] + ssq2[3][P2];
      const float ip = rsqrtf(sq);
      float bz = -1e30f; int bvi = 0;
      #pragma unroll
      for (int ni=0;ni<8;ni++){                  // ni ascending => v ascending
        const float z = f4c(*(const float4*)&acc[mi][ni], r) * ip * iw[ni];
        const int vv = wv*128 + ni*16 + col;
        zf[(p0+P2)*VCN + vv] = __float2half(z);
        if (z > bz){ bz = z; bvi = vv; }
      }
      #pragma unroll
      for (int off=1; off<16; off<<=1){
        const float oz = __shfl_xor(bz, off);
        const int  oi = __shfl_xor(bvi, off);
        if (oz > bz || (oz == bz && oi < bvi)){ bz = oz; bvi = oi; }
      }
      if (col == 0){ rv[P2][wv] = bz; ri[P2][wv] = bvi; }
    }
  }
  __syncthreads();
  if (t < 32){
    float best = rv[t][0]; int bi = ri[t][0];
    #pragma unroll
    for (int s=1;s<4;s++){                       // wave (v-quadrant) ascending
      float z2 = rv[t][s]; int i2 = ri[t][s];
      if (z2 > best || (z2 == best && i2 < bi)){ best = z2; bi = i2; }
    }
    pbest[p0+t] = best; pbidx[p0+t] = bi;
  }
}

// ---------------- per-patch selection -> inpf split-frag directly ----------------
// inpf: 2-split frag layout, R=NPATCH rows (rt=q>>4), kkc=10.
__global__ __launch_bounds__(64) void select_k(
    const float* __restrict__ x, const float* __restrict__ cw,
    const __half* __restrict__ zf,
    const float* __restrict__ pbest, const int* __restrict__ pbidx,
    u16* __restrict__ inpf){
  __shared__ float wlds[256];
  __shared__ float xcol[256];
  __shared__ float simv[64];
  const int q = blockIdx.x;
  const int lane = threadIdx.x;
  const int n = q / LPP, l = q % LPP;
  const int oy = l / OHW, ox = l % OHW;
  const int pl = (oy*3 + (lane >> 3))*HWD + (ox*3 + (lane & 7));
  const int p = n*PIXN + pl;
  const int rt = q >> 4, ql = q & 15;
  float val = pbest[p];
  int flat = pbidx[p]*64 + lane;                 // v-major flat index, pos=lane
  #pragma unroll
  for (int off=32; off>0; off>>=1){
    float ov = __shfl_xor(val, off);
    int of = __shfl_xor(flat, off);
    if (ov > val || (ov == val && of < flat)){ val = ov; flat = of; }
  }
  const int mch = flat >> 6;
  const int pos = flat & 63;
  const float ms = val;
  *(float4*)&wlds[lane*4] = *(const float4*)&cw[(size_t)mch*CHN + lane*4];
  simv[lane] = __half2float(zf[(size_t)p*VCN + mch]);
  // gather winning pixel's channel column from fp32 x (L3-resident)
  const int wpl = (oy*3 + (pos>>3))*HWD + (ox*3 + (pos&7));
  const float* xb = x + (size_t)n*CHN*PIXN + wpl;
  #pragma unroll
  for (int j=0;j<4;j++) xcol[lane*4+j] = xb[(size_t)(lane*4+j)*PIXN];
  __syncthreads();
  // integ: lanes 0..31 handle channels c0..c0+7 (one us8 chunk per split)
  if (lane < 32){
    const int kk = lane >> 2, qr = lane & 3;
    const float om = 1.0f - ms;
    const int c0 = kk*32 + qr*8;
    us8 p1, p2;
    #pragma unroll
    for (int j=0;j<8;j++){
      float v = fmaf(xcol[c0+j], ms, wlds[c0+j]*om);
      u16 s1 = bfrn(v);
      p1[j] = s1; p2[j] = bfrn(v - bf2f(s1));
    }
    const size_t ob = ((size_t)(rt*10 + kk)*2)*512 + (qr*16 + ql)*8;
    *(us8*)&inpf[ob]     = p1;
    *(us8*)&inpf[ob+512] = p2;
  }
  // sims: channels 256..319 -> chunks kk in {8,9}; 16 tasks = (s, kk, qr)
  if (lane < 16){
    const int s = lane >> 3, kk = 8 + ((lane >> 2) & 1), qr = lane & 3;
    us8 pv;
    #pragma unroll
    for (int j=0;j<8;j++){
      float v = simv[(kk-8)*32 + qr*8 + j];
      u16 s1 = bfrn(v);
      pv[j] = (s == 0) ? s1 : bfrn(v - bf2f(s1));
    }
    const size_t ob = ((size_t)(rt*10 + kk)*2 + s)*512 + (qr*16 + ql)*8;
    *(us8*)&inpf[ob] = pv;
  }
}

// ---------------- MLP layer 1: split-frag in, split-frag out (h1f) ----------------
__global__ __launch_bounds__(256,2) void mlp1_k(
    const u16* __restrict__ af, const u16* __restrict__ bf,
    const float* __restrict__ bias, u16* __restrict__ h1f){
  const int kkc = INPD >> 5;     // 10
  const int t = threadIdx.x;
  const int n0 = blockIdx.x*128, m0 = blockIdx.y*128;
  const int lane = t&63, wv = t>>6;
  const int mq = wv&1, nq = wv>>1;
  const int col = lane&15, qr = lane>>4;
  const size_t loff = (size_t)lane*8;
  const int ptA0 = (m0>>4) + mq*4;
  const int ntB0 = (n0>>4) + nq*4;
  f32x4 acc[4][4];
  #pragma unroll
  for (int i=0;i<4;i++)
    #pragma unroll
    for (int j=0;j<4;j++) acc[i][j] = (f32x4){0.f,0.f,0.f,0.f};

  for (int kk=0; kk<kkc; kk++){
    bf16x8 a[4][2];
    #pragma unroll
    for (int mi=0;mi<4;mi++){
      const size_t ab = (((size_t)(ptA0+mi)*kkc + kk)*2)*512 + loff;
      a[mi][0] = *(const bf16x8*)&af[ab];
      a[mi][1] = *(const bf16x8*)&af[ab+512];
    }
    #pragma unroll
    for (int ni=0;ni<4;ni++){
      const size_t bb = (((size_t)(ntB0+ni)*kkc + kk)*2)*512 + loff;
      const bf16x8 b1 = *(const bf16x8*)&bf[bb];
      const bf16x8 b2 = *(const bf16x8*)&bf[bb+512];
      #pragma unroll
      for (int mi=0;mi<4;mi++){
        f32x4 c = acc[mi][ni];
        c = __builtin_amdgcn_mfma_f32_16x16x32_bf16(a[mi][0], b1, c, 0,0,0);
        c = __builtin_amdgcn_mfma_f32_16x16x32_bf16(a[mi][0], b2, c, 0,0,0);
        c = __builtin_amdgcn_mfma_f32_16x16x32_bf16(a[mi][1], b1, c, 0,0,0);
        acc[mi][ni] = c;
      }
    }
  }
  float bb4[4];
  #pragma unroll
  for (int ni=0;ni<4;ni++) bb4[ni] = bias[n0 + nq*64 + ni*16 + col];
  // epilogue: leaky-relu then 2-way split store into h1f frag layout (kkc2=24).
  // pad rows (>=7200) contain finite junk; consumed only by discarded rows.
  #pragma unroll
  for (int mi=0;mi<4;mi++){
    const int rt2 = (m0>>4) + mq*4 + mi;
    #pragma unroll
    for (int r=0;r<4;r++){
      #pragma unroll
      for (int ni=0;ni<4;ni++){
        float v = f4c(*(const float4*)&acc[mi][ni], r) + bb4[ni];
        v = v > 0.f ? v : 0.2f*v;
        u16 s1 = bfrn(v);
        u16 s2 = bfrn(v - bf2f(s1));
        const int kk2 = (n0>>5) + nq*2 + (ni>>1);
        const int qn = (ni&1)*2 + (col>>3);
        const size_t ob = ((size_t)(rt2*24 + kk2)*2)*512 + (qn*16 + qr*4 + r)*8 + (col&7);
        h1f[ob] = s1; h1f[ob+512] = s2;
      }
    }
  }
}

// ---------------- MLP layer 2: split-frag in, fp32 out + tanh ----------------
__global__ __launch_bounds__(256,2) void mlp2_k(
    const u16* __restrict__ af, const u16* __restrict__ bf,
    const float* __restrict__ bias, float* __restrict__ C){
  const int kkc = HID >> 5;      // 24
  const int t = threadIdx.x;
  const int n0 = blockIdx.x*128, m0 = blockIdx.y*128;
  const int lane = t&63, wv = t>>6;
  const int mq = wv&1, nq = wv>>1;
  const int col = lane&15, qr = lane>>4;
  const size_t loff = (size_t)lane*8;
  const int ptA0 = (m0>>4) + mq*4;
  const int ntB0 = (n0>>4) + nq*4;
  f32x4 acc[4][4];
  #pragma unroll
  for (int i=0;i<4;i++)
    #pragma unroll
    for (int j=0;j<4;j++) acc[i][j] = (f32x4){0.f,0.f,0.f,0.f};

  for (int kk=0; kk<kkc; kk++){
    bf16x8 a[4][2];
    #pragma unroll
    for (int mi=0;mi<4;mi++){
      const size_t ab = (((size_t)(ptA0+mi)*kkc + kk)*2)*512 + loff;
      a[mi][0] = *(const bf16x8*)&af[ab];
      a[mi][1] = *(const bf16x8*)&af[ab+512];
    }
    #pragma unroll
    for (int ni=0;ni<4;ni++){
      const size_t bb = (((size_t)(ntB0+ni)*kkc + kk)*2)*512 + loff;
      const bf16x8 b1 = *(const bf16x8*)&bf[bb];
      const bf16x8 b2 = *(const bf16x8*)&bf[bb+512];
      #pragma unroll
      for (int mi=0;mi<4;mi++){
        f32x4 c = acc[mi][ni];
        c = __builtin_amdgcn_mfma_f32_16x16x32_bf16(a[mi][0], b1, c, 0,0,0);
        c = __builtin_amdgcn_mfma_f32_16x16x32_bf16(a[mi][0], b2, c, 0,0,0);
        c = __builtin_amdgcn_mfma_f32_16x16x32_bf16(a[mi][1], b1, c, 0,0,0);
        acc[mi][ni] = c;
      }
    }
  }
  float bb4[4];
  #pragma unroll
  for (int ni=0;ni<4;ni++) bb4[ni] = bias[n0 + nq*64 + ni*16 + col];
  #pragma unroll
  for (int mi=0;mi<4;mi++){
    #pragma unroll
    for (int r=0;r<4;r++){
      const int row = m0 + mq*64 + mi*16 + qr*4 + r;
      if (row < NPATCH){
        #pragma unroll
        for (int ni=0;ni<4;ni++){
          float v = f4c(*(const float4*)&acc[mi][ni], r) + bb4[ni];
          C[(size_t)row*CHN + n0 + nq*64 + ni*16 + col] = tanhf(v);
        }
      }
    }
  }
}

extern "C" void kernel_launch(void* const* d_in, const int* in_sizes, int n_in,
                              void* d_out, int out_size, void* d_ws, size_t ws_size,
                              hipStream_t stream){
  const float* x  = (const float*)d_in[0];
  const float* cw = (const float*)d_in[1];
  const float* W1 = (const float*)d_in[2];
  const float* b1 = (const float*)d_in[3];
  const float* W2 = (const float*)d_in[4];
  const float* b2 = (const float*)d_in[5];
  float* out = (float*)d_out;
  float* ws = (float*)d_ws;
  float* invw  = ws;                                     // 512
  float* pbest = invw + VCN;                             // TOTPIX
  int*   pbidx = (int*)(pbest + TOTPIX);                 // TOTPIX
  u16*   wf    = (u16*)(pbidx + TOTPIX);                 // 32*8*3*512 u16
  u16*   w1f   = wf + (size_t)32*8*3*512;
  u16*   w2f   = w1f + (size_t)48*10*2*512;
  u16*   inpf  = w2f + (size_t)16*24*2*512;              // MTP*10*2*512 (9.3 MB)
  __half* zf   = (__half*)(inpf + (size_t)MTP*10*2*512); // 75.5 MB
  u16*   h1f   = (u16*)zf;  // alias: zf dead after select_k; h1f written after
  // total ws use ~88 MB

  prep_k<<<1632,64,0,stream>>>(cw, W1, W2, wf, w1f, w2f, invw);
  gemm_z_k<<<TOTPIX/32,256,0,stream>>>(x, wf, invw, pbest, pbidx, zf);
  select_k<<<NPATCH,64,0,stream>>>(x, cw, zf, pbest, pbidx, inpf);
  mlp1_k<<<dim3(HID/128, (NPATCH+127)/128),256,0,stream>>>(inpf, w1f, b1, h1f);
  mlp2_k<<<dim3(CHN/128, (NPATCH+127)/128),256,0,stream>>>(h1f, w2f, b2, out);
}